// Round 9
// baseline (305.190 us; speedup 1.0000x reference)
//
#include <hip/hip_runtime.h>
#include <hip/hip_bf16.h>
#include <math.h>

// ---------------------------------------------------------------------------
// VQ quantizer + 6-layer ReLU MLP via split-bf16 MFMA.
//   f32 GEMM ~= Ah*Bh + Ah*Bl + Al*Bh  (drop lo*lo ~2^-16 rel)
//   R9: gemm_mid v4 = 128x256 tile BK=32 (staging-bound fix: bytes/FLOP 2x
//       down), splitK2 mids / splitK8 L6. fused_pre v3 = pk-f32 with TWO
//       independent chains (4 elems/lane), split-wave TLP.
// Workspace map (40MB):
//   [0..16M)  phase1: qhi@0(1M), wihi@1M, wilo@3M   (dead after L1)
//             phase2: mid partial p0@0(8M), p1@8M
//             phase3: wohi@0(2M), wolo@2M
//   [16..24M) h planes: hhi@16M, hlo@20M
//   [24..40M) whhi@24M, whlo@32M (dead after mids) -> phase3: l6par@24M(16M)
// ---------------------------------------------------------------------------

#define B_ROWS 1024
#define D_IN   512
#define HDIM   2048
#define NTOT   (B_ROWS * D_IN)
#define NCODE  256
#define EDIM   8

typedef __attribute__((ext_vector_type(8))) short bf16x8;
typedef __attribute__((ext_vector_type(4))) float f32x4;
typedef __attribute__((ext_vector_type(2))) float f32x2;

__device__ inline void gload_lds16(const void* g, void* l) {
    __builtin_amdgcn_global_load_lds(
        (const __attribute__((address_space(1))) void*)g,
        (__attribute__((address_space(3))) void*)l, 16, 0, 0);
}

__device__ inline ushort bf16_hi_bits(float v, float* hi_f) {
    __hip_bfloat16 h = __float2bfloat16(v);
    *hi_f = __bfloat162float(h);
    ushort u; __builtin_memcpy(&u, &h, 2); return u;
}
__device__ inline ushort bf16_bits(float v) {
    __hip_bfloat16 h = __float2bfloat16(v);
    ushort u; __builtin_memcpy(&u, &h, 2); return u;
}

// ---------------- fused: quantize (blocks 0..511) + wi/wh split --------------
// Quantize v3: packed f32, 4 elems/lane as TWO independent pk chains.
// Per-element arithmetic bit-identical to the R5/R8-passing kernels:
//   dot_e = RN(p2_e*w_e + dot_{e-1}); d = RN(RN(sm+Ek) - dot).
__global__ __launch_bounds__(256) void fused_pre(
    const float* __restrict__ x, const float* __restrict__ embW,
    const float* __restrict__ Wi, const float* __restrict__ Wh,
    ushort* __restrict__ qhi,
    ushort* __restrict__ wihi, ushort* __restrict__ wilo,
    ushort* __restrict__ whhi, ushort* __restrict__ whlo,
    float* __restrict__ loss_out)
{
    __shared__ float sD[NCODE][20];   // 80B rows: {w,w}x8 [0..15], {E,E} [16..17]
    const int tid = threadIdx.x;

    if (blockIdx.x >= 512) {
        // ---- weight split: 1280 blocks x 256 thr x 4 float4 ----
        const int sidx = blockIdx.x - 512;
        #pragma unroll
        for (int s = 0; s < 4; ++s) {
            const int g = sidx * 1024 + s * 256 + tid;   // < 1310720
            const float* src; ushort* hi; ushort* lo; int j;
            if (g < 262144) { src = Wi; hi = wihi; lo = wilo; j = g; }
            else            { src = Wh; hi = whhi; lo = whlo; j = g - 262144; }
            float4 v = reinterpret_cast<const float4*>(src)[j];
            float f[4] = {v.x, v.y, v.z, v.w};
            ushort hh[4], ll[4];
            #pragma unroll
            for (int c = 0; c < 4; ++c) {
                float hf;
                hh[c] = bf16_hi_bits(f[c], &hf);
                ll[c] = bf16_bits(f[c] - hf);
            }
            ushort4 h4 = {hh[0], hh[1], hh[2], hh[3]};
            ushort4 l4 = {ll[0], ll[1], ll[2], ll[3]};
            reinterpret_cast<ushort4*>(hi)[j] = h4;
            reinterpret_cast<ushort4*>(lo)[j] = l4;
        }
        return;
    }

    // ---- codebook row k -> duplicated pairs + E (numpy pairwise order) ----
    {
        const float4 a4 = *reinterpret_cast<const float4*>(&embW[tid * EDIM]);
        const float4 b4 = *reinterpret_cast<const float4*>(&embW[tid * EDIM + 4]);
        float s0 = __fmul_rn(a4.x, a4.x), s1 = __fmul_rn(a4.y, a4.y);
        float s2 = __fmul_rn(a4.z, a4.z), s3 = __fmul_rn(a4.w, a4.w);
        float s4 = __fmul_rn(b4.x, b4.x), s5 = __fmul_rn(b4.y, b4.y);
        float s6 = __fmul_rn(b4.z, b4.z), s7 = __fmul_rn(b4.w, b4.w);
        float a = __fadd_rn(__fadd_rn(s0, s1), __fadd_rn(s2, s3));
        float b = __fadd_rn(__fadd_rn(s4, s5), __fadd_rn(s6, s7));
        float E = __fadd_rn(a, b);
        float* r = sD[tid];
        r[0]  = a4.x; r[1]  = a4.x; r[2]  = a4.y; r[3]  = a4.y;
        r[4]  = a4.z; r[5]  = a4.z; r[6]  = a4.w; r[7]  = a4.w;
        r[8]  = b4.x; r[9]  = b4.x; r[10] = b4.y; r[11] = b4.y;
        r[12] = b4.z; r[13] = b4.z; r[14] = b4.w; r[15] = b4.w;
        r[16] = E;    r[17] = E;
    }
    __syncthreads();

    const int nbase = blockIdx.x * 1024 + tid;   // elems nbase + {0,256,512,768}

    float p2a[4][EDIM], sm[4];
    #pragma unroll
    for (int j = 0; j < 4; ++j) {
        const float v = x[nbase + j * 256];
        float p[EDIM];
        #pragma unroll
        for (int e = 0; e < EDIM; ++e)
            p[e] = powf(v, (float)(e + 1));        // match np.power f32
        float a = __fadd_rn(__fadd_rn(p[0], p[1]), __fadd_rn(p[2], p[3]));
        float b = __fadd_rn(__fadd_rn(p[4], p[5]), __fadd_rn(p[6], p[7]));
        sm[j] = __fadd_rn(a, b);
        #pragma unroll
        for (int e = 0; e < EDIM; ++e)
            p2a[j][e] = 2.0f * p[e];               // exact pow2 fold
    }

    f32x2 pA[EDIM], pB[EDIM];
    #pragma unroll
    for (int e = 0; e < EDIM; ++e) {
        pA[e].x = p2a[0][e]; pA[e].y = p2a[1][e];
        pB[e].x = p2a[2][e]; pB[e].y = p2a[3][e];
    }
    f32x2 smA; smA.x = sm[0]; smA.y = sm[1];
    f32x2 smB; smB.x = sm[2]; smB.y = sm[3];
    f32x2 neg1; neg1.x = -1.0f; neg1.y = -1.0f;

    float best[4] = {INFINITY, INFINITY, INFINITY, INFINITY};
    int   bi[4]   = {0, 0, 0, 0};

    #pragma unroll 2
    for (int k = 0; k < NCODE; ++k) {
        const f32x2* r2 = reinterpret_cast<const f32x2*>(sD[k]);
        f32x2 w0 = r2[0], w1 = r2[1], w2 = r2[2], w3 = r2[3];
        f32x2 w4 = r2[4], w5 = r2[5], w6 = r2[6], w7 = r2[7];
        f32x2 ek = r2[8];

        f32x2 dA, dB;
        asm("v_pk_mul_f32 %0, %1, %2"     : "=v"(dA) : "v"(pA[0]), "v"(w0));
        asm("v_pk_mul_f32 %0, %1, %2"     : "=v"(dB) : "v"(pB[0]), "v"(w0));
        asm("v_pk_fma_f32 %0, %1, %2, %0" : "+v"(dA) : "v"(pA[1]), "v"(w1));
        asm("v_pk_fma_f32 %0, %1, %2, %0" : "+v"(dB) : "v"(pB[1]), "v"(w1));
        asm("v_pk_fma_f32 %0, %1, %2, %0" : "+v"(dA) : "v"(pA[2]), "v"(w2));
        asm("v_pk_fma_f32 %0, %1, %2, %0" : "+v"(dB) : "v"(pB[2]), "v"(w2));
        asm("v_pk_fma_f32 %0, %1, %2, %0" : "+v"(dA) : "v"(pA[3]), "v"(w3));
        asm("v_pk_fma_f32 %0, %1, %2, %0" : "+v"(dB) : "v"(pB[3]), "v"(w3));
        asm("v_pk_fma_f32 %0, %1, %2, %0" : "+v"(dA) : "v"(pA[4]), "v"(w4));
        asm("v_pk_fma_f32 %0, %1, %2, %0" : "+v"(dB) : "v"(pB[4]), "v"(w4));
        asm("v_pk_fma_f32 %0, %1, %2, %0" : "+v"(dA) : "v"(pA[5]), "v"(w5));
        asm("v_pk_fma_f32 %0, %1, %2, %0" : "+v"(dB) : "v"(pB[5]), "v"(w5));
        asm("v_pk_fma_f32 %0, %1, %2, %0" : "+v"(dA) : "v"(pA[6]), "v"(w6));
        asm("v_pk_fma_f32 %0, %1, %2, %0" : "+v"(dB) : "v"(pB[6]), "v"(w6));
        asm("v_pk_fma_f32 %0, %1, %2, %0" : "+v"(dA) : "v"(pA[7]), "v"(w7));
        asm("v_pk_fma_f32 %0, %1, %2, %0" : "+v"(dB) : "v"(pB[7]), "v"(w7));
        f32x2 sA, sB;
        asm("v_pk_add_f32 %0, %1, %2"     : "=v"(sA) : "v"(smA), "v"(ek));
        asm("v_pk_add_f32 %0, %1, %2"     : "=v"(sB) : "v"(smB), "v"(ek));
        f32x2 ddA, ddB;
        asm("v_pk_fma_f32 %0, %1, %2, %3" : "=v"(ddA) : "v"(dA), "v"(neg1), "v"(sA));
        asm("v_pk_fma_f32 %0, %1, %2, %3" : "=v"(ddB) : "v"(dB), "v"(neg1), "v"(sB));

        float d0 = ddA.x, d1 = ddA.y, d2 = ddB.x, d3 = ddB.y;
        bi[0] = (d0 < best[0]) ? k : bi[0]; best[0] = fminf(best[0], d0);
        bi[1] = (d1 < best[1]) ? k : bi[1]; best[1] = fminf(best[1], d1);
        bi[2] = (d2 < best[2]) ? k : bi[2]; best[2] = fminf(best[2], d2);
        bi[3] = (d3 < best[3]) ? k : bi[3]; best[3] = fminf(best[3], d3);
    }

    #pragma unroll
    for (int j = 0; j < 4; ++j) {
        const int n = nbase + j * 256;
        qhi[(n & (B_ROWS - 1)) * D_IN + (n >> 10)] = bf16_bits((float)bi[j]);
    }
    if (blockIdx.x == 0 && tid == 0) loss_out[0] = 0.0f;
}

// ---------------- wo split (after mids; writes into freed partial region) ----
__global__ __launch_bounds__(256) void wo_split(
    const float* __restrict__ Wo, ushort* __restrict__ hi, ushort* __restrict__ lo)
{
    const int tid = threadIdx.x;
    #pragma unroll
    for (int s = 0; s < 4; ++s) {
        const int j = blockIdx.x * 1024 + s * 256 + tid;   // < 262144
        float4 v = reinterpret_cast<const float4*>(Wo)[j];
        float f[4] = {v.x, v.y, v.z, v.w};
        ushort hh[4], ll[4];
        #pragma unroll
        for (int c = 0; c < 4; ++c) {
            float hf;
            hh[c] = bf16_hi_bits(f[c], &hf);
            ll[c] = bf16_bits(f[c] - hf);
        }
        ushort4 h4 = {hh[0], hh[1], hh[2], hh[3]};
        ushort4 l4 = {ll[0], ll[1], ll[2], ll[3]};
        reinterpret_cast<ushort4*>(hi)[j] = h4;
        reinterpret_cast<ushort4*>(lo)[j] = l4;
    }
}

// ---------------- L1 GEMM (R3-proven): block 64x128, wave 32x64, BK=64 -------
template<bool ALO, bool PARTIAL>
__global__ __launch_bounds__(256) void gemm_split(
    const ushort* __restrict__ Ahi, const ushort* __restrict__ Alo,
    const ushort* __restrict__ Whi, const ushort* __restrict__ Wlo,
    const float* __restrict__ bias,
    ushort* __restrict__ Ohi, ushort* __restrict__ Olo,
    float* __restrict__ OF, int N, int K, int klen)
{
    constexpr int BUF = 49152;
    constexpr int OFF_AH = 0, OFF_AL = 8192, OFF_BH = 16384;
    __shared__ char lds[2 * BUF];

    const int tid = threadIdx.x, lane = tid & 63, wid = tid >> 6;

    const int gy = gridDim.y;
    const int nwg = gridDim.x * gy;
    int lin = blockIdx.x * gy + blockIdx.y;
    int q   = nwg >> 3;
    int sw  = (lin & 7) * q + (lin >> 3);
    int bx  = sw / gy, by2 = sw % gy;
    const int bm   = (by2 & 15) << 6;
    const int kz   = by2 >> 4;
    const int kbeg = kz * klen;
    const int bn   = bx << 7;

    const int wm = (wid >> 1) << 5;
    const int wn = (wid & 1) << 6;

    constexpr int NSEGW = ALO ? 12 : 10;
    const ushort* gp[NSEGW];
    uint ldsoff[NSEGW];
    #pragma unroll
    for (int i = 0; i < NSEGW; ++i) {
        int s = wid + i * 4;
        const ushort* pl; int row0, base, sip;
        if (ALO) {
            if (s < 8)       { pl = Ahi; row0 = bm; base = OFF_AH;         sip = s; }
            else if (s < 16) { pl = Alo; row0 = bm; base = OFF_AL;         sip = s - 8; }
            else if (s < 32) { pl = Whi; row0 = bn; base = OFF_BH;         sip = s - 16; }
            else             { pl = Wlo; row0 = bn; base = OFF_BH + 16384; sip = s - 32; }
        } else {
            if (s < 8)       { pl = Ahi; row0 = bm; base = OFF_AH;         sip = s; }
            else if (s < 24) { pl = Whi; row0 = bn; base = OFF_BH;         sip = s - 8; }
            else             { pl = Wlo; row0 = bn; base = OFF_BH + 16384; sip = s - 24; }
        }
        int r  = sip * 8 + (lane >> 3);
        int ch = (lane & 7) ^ (r & 7);
        gp[i]     = pl + (size_t)(row0 + r) * K + kbeg + ch * 8;
        ldsoff[i] = base + sip * 1024;
    }

    uint aoff[2][2], boff[4][2];
    #pragma unroll
    for (int f = 0; f < 2; ++f) {
        int ar = wm + f * 16 + (lane & 15);
        #pragma unroll
        for (int s = 0; s < 2; ++s) {
            int ch = (s * 4 + (lane >> 4)) ^ (ar & 7);
            aoff[f][s] = OFF_AH + ar * 128 + ch * 16;
        }
    }
    #pragma unroll
    for (int f = 0; f < 4; ++f) {
        int br = wn + f * 16 + (lane & 15);
        #pragma unroll
        for (int s = 0; s < 2; ++s) {
            int ch = (s * 4 + (lane >> 4)) ^ (br & 7);
            boff[f][s] = OFF_BH + br * 128 + ch * 16;
        }
    }

    auto stage = [&](int kt, int b) {
        #pragma unroll
        for (int i = 0; i < NSEGW; ++i)
            gload_lds16(gp[i] + kt * 64, lds + b * BUF + ldsoff[i]);
    };

    f32x4 acc[2][4] = {};
    const int NT = klen >> 6;

    stage(0, 0);
    __syncthreads();

    for (int t = 0; t < NT; ++t) {
        const int cur = t & 1;
        if (t + 1 < NT) stage(t + 1, cur ^ 1);

        const char* lb = lds + cur * BUF;
        bf16x8 aH[2][2], aL[2][2], bH[2][4], bL[2][4];
        #pragma unroll
        for (int s = 0; s < 2; ++s) {
            #pragma unroll
            for (int f = 0; f < 2; ++f) {
                aH[s][f] = *(const bf16x8*)(lb + aoff[f][s]);
                if constexpr (ALO) aL[s][f] = *(const bf16x8*)(lb + aoff[f][s] + 8192);
            }
            #pragma unroll
            for (int f = 0; f < 4; ++f) {
                bH[s][f] = *(const bf16x8*)(lb + boff[f][s]);
                bL[s][f] = *(const bf16x8*)(lb + boff[f][s] + 16384);
            }
        }
        #pragma unroll
        for (int s = 0; s < 2; ++s) {
            #pragma unroll
            for (int fm = 0; fm < 2; ++fm)
                #pragma unroll
                for (int fn = 0; fn < 4; ++fn)
                    acc[fm][fn] = __builtin_amdgcn_mfma_f32_16x16x32_bf16(
                        aH[s][fm], bH[s][fn], acc[fm][fn], 0, 0, 0);
            #pragma unroll
            for (int fm = 0; fm < 2; ++fm)
                #pragma unroll
                for (int fn = 0; fn < 4; ++fn)
                    acc[fm][fn] = __builtin_amdgcn_mfma_f32_16x16x32_bf16(
                        aH[s][fm], bL[s][fn], acc[fm][fn], 0, 0, 0);
            if constexpr (ALO) {
                #pragma unroll
                for (int fm = 0; fm < 2; ++fm)
                    #pragma unroll
                    for (int fn = 0; fn < 4; ++fn)
                        acc[fm][fn] = __builtin_amdgcn_mfma_f32_16x16x32_bf16(
                            aL[s][fm], bH[s][fn], acc[fm][fn], 0, 0, 0);
            }
        }
        __syncthreads();
    }

    #pragma unroll
    for (int fm = 0; fm < 2; ++fm) {
        #pragma unroll
        for (int fn = 0; fn < 4; ++fn) {
            const int col = bn + wn + fn * 16 + (lane & 15);
            const int rb  = bm + wm + fm * 16 + ((lane >> 4) << 2);
            if constexpr (PARTIAL) {
                #pragma unroll
                for (int r = 0; r < 4; ++r)
                    OF[(size_t)(kz * B_ROWS + rb + r) * N + col] = acc[fm][fn][r];
            } else {
                const float bc = bias[col];
                #pragma unroll
                for (int r = 0; r < 4; ++r) {
                    float v = acc[fm][fn][r] + bc;
                    v = v > 0.f ? v : 0.f;
                    float hf;
                    ushort hb = bf16_hi_bits(v, &hf);
                    Ohi[(size_t)(rb + r) * N + col] = hb;
                    Olo[(size_t)(rb + r) * N + col] = bf16_bits(v - hf);
                }
            }
        }
    }
}

// ---------------- mid/L6 GEMM v4: 128x256 tile, BK=32, 96KB LDS dbuf ---------
// 4 waves, wave 64x128. Staging-efficiency tile: (BM*BN)/(BM+BN)=85.
// Swizzle pair (proven R6/R7): src chunk = (lane&3)^((r>>1)&3);
// read chunk = (lane>>4)^((row>>1)&3). Raw f32 partial out (split-K).
__global__ __launch_bounds__(256) void gemm_mid(
    const ushort* __restrict__ Ahi, const ushort* __restrict__ Alo,
    const ushort* __restrict__ Bhi, const ushort* __restrict__ Blo,
    float* __restrict__ OF, int N, int Kfull, int klen)
{
    constexpr int BUF = 49152;   // Ahi@0(8K) Alo@8K Bhi@16K(16K) Blo@32K(16K)
    __shared__ char lds[2 * BUF];

    const int tid = threadIdx.x, lane = tid & 63, wid = tid >> 6;

    // bijective XCD swizzle, column-major linearization (nwg = 128, %8==0)
    const int gy = gridDim.y;
    const int nwg = gridDim.x * gy;
    int lin = blockIdx.x * gy + blockIdx.y;
    int q   = nwg >> 3;
    int sw  = (lin & 7) * q + (lin >> 3);
    int bx  = sw / gy, by2 = sw % gy;
    const int bm   = (by2 & 7) << 7;     // 8 m-tiles of 128
    const int kz   = by2 >> 3;
    const int kbeg = kz * klen;
    const int bn   = bx << 8;            // 256-wide n-tiles

    const int wm = (wid >> 1) << 6;      // 0,64
    const int wn = (wid & 1) << 7;       // 0,128

    // ---- stage: 48 segs of 1KB (16 rows x 64B); wave w: segs w+4i, i<12 ----
    const int r_l = lane >> 2;
    const int chs = (lane & 3) ^ ((r_l >> 1) & 3);
    const ushort* gp[12];
    uint ldsoff[12];
    #pragma unroll
    for (int i = 0; i < 12; ++i) {
        const int s = wid + i * 4;
        const ushort* pl; int row0; uint base;
        if (s < 8)       { pl = Ahi; row0 = bm + s * 16;        base = (uint)s * 1024; }
        else if (s < 16) { pl = Alo; row0 = bm + (s - 8) * 16;  base = 8192  + (uint)(s - 8)  * 1024; }
        else if (s < 32) { pl = Bhi; row0 = bn + (s - 16) * 16; base = 16384 + (uint)(s - 16) * 1024; }
        else             { pl = Blo; row0 = bn + (s - 32) * 16; base = 32768 + (uint)(s - 32) * 1024; }
        gp[i]     = pl + (size_t)(row0 + r_l) * Kfull + kbeg + chs * 8;
        ldsoff[i] = base;
    }

    // ---- frag offsets (64B rows, 4 chunks) ----
    uint aoff[4], boff[8];
    #pragma unroll
    for (int f = 0; f < 4; ++f) {
        const int ar = wm + f * 16 + (lane & 15);
        aoff[f] = (uint)(ar * 64 + ((((lane >> 4)) ^ ((ar >> 1) & 3)) << 4));
    }
    #pragma unroll
    for (int f = 0; f < 8; ++f) {
        const int br = wn + f * 16 + (lane & 15);
        boff[f] = (uint)(16384 + br * 64 + ((((lane >> 4)) ^ ((br >> 1) & 3)) << 4));
    }

    auto stage = [&](int kt, int b) {
        #pragma unroll
        for (int i = 0; i < 12; ++i)
            gload_lds16(gp[i] + kt * 32, lds + b * BUF + ldsoff[i]);
    };

    f32x4 acc[4][8] = {};
    const int NT = klen >> 5;

    stage(0, 0);
    __syncthreads();

    for (int t = 0; t < NT; ++t) {
        const int cur = t & 1;
        if (t + 1 < NT) stage(t + 1, cur ^ 1);   // issue next tile's DMA first

        const char* lb = lds + cur * BUF;
        // term 1: Ah*Bh
        bf16x8 aH[4], bH[8];
        #pragma unroll
        for (int f = 0; f < 4; ++f) aH[f] = *(const bf16x8*)(lb + aoff[f]);
        #pragma unroll
        for (int f = 0; f < 8; ++f) bH[f] = *(const bf16x8*)(lb + boff[f]);
        #pragma unroll
        for (int fm = 0; fm < 4; ++fm)
            #pragma unroll
            for (int fn = 0; fn < 8; ++fn)
                acc[fm][fn] = __builtin_amdgcn_mfma_f32_16x16x32_bf16(
                    aH[fm], bH[fn], acc[fm][fn], 0, 0, 0);
        // term 3: Al*Bh (bH dies after)
        {
            bf16x8 aL[4];
            #pragma unroll
            for (int f = 0; f < 4; ++f) aL[f] = *(const bf16x8*)(lb + aoff[f] + 8192);
            #pragma unroll
            for (int fm = 0; fm < 4; ++fm)
                #pragma unroll
                for (int fn = 0; fn < 8; ++fn)
                    acc[fm][fn] = __builtin_amdgcn_mfma_f32_16x16x32_bf16(
                        aL[fm], bH[fn], acc[fm][fn], 0, 0, 0);
        }
        // term 2: Ah*Bl
        {
            bf16x8 bL[8];
            #pragma unroll
            for (int f = 0; f < 8; ++f) bL[f] = *(const bf16x8*)(lb + boff[f] + 16384);
            #pragma unroll
            for (int fm = 0; fm < 4; ++fm)
                #pragma unroll
                for (int fn = 0; fn < 8; ++fn)
                    acc[fm][fn] = __builtin_amdgcn_mfma_f32_16x16x32_bf16(
                        aH[fm], bL[fn], acc[fm][fn], 0, 0, 0);
        }
        __syncthreads();   // drains vmcnt+lgkm: next DMA landed, reads done
    }

    // partial f32 epilogue: C layout col=lane&15, row=(lane>>4)*4+r
    #pragma unroll
    for (int fm = 0; fm < 4; ++fm) {
        #pragma unroll
        for (int fn = 0; fn < 8; ++fn) {
            const int col = bn + wn + fn * 16 + (lane & 15);
            const int rb  = bm + wm + fm * 16 + ((lane >> 4) << 2);
            #pragma unroll
            for (int r = 0; r < 4; ++r)
                OF[(size_t)(kz * B_ROWS + rb + r) * N + col] = acc[fm][fn][r];
        }
    }
}

// ---------------- mid combine: h = relu(p0+p1+bias) -> hi/lo planes ----------
__global__ __launch_bounds__(256) void combine_mid(
    const float* __restrict__ part, const float* __restrict__ bias,
    ushort* __restrict__ hi, ushort* __restrict__ lo)
{
    const int i = blockIdx.x * 256 + threadIdx.x;     // over 524288 float4
    const float4* p = (const float4*)part;
    float4 a = p[i], b = p[i + 524288];
    float4 bb = ((const float4*)bias)[i & 511];
    float f[4] = {a.x + b.x + bb.x, a.y + b.y + bb.y,
                  a.z + b.z + bb.z, a.w + b.w + bb.w};
    ushort hh[4], ll[4];
    #pragma unroll
    for (int c = 0; c < 4; ++c) {
        float v = f[c] > 0.f ? f[c] : 0.f;
        float hf;
        hh[c] = bf16_hi_bits(v, &hf);
        ll[c] = bf16_bits(v - hf);
    }
    ushort4 h4 = {hh[0], hh[1], hh[2], hh[3]};
    ushort4 l4 = {ll[0], ll[1], ll[2], ll[3]};
    reinterpret_cast<ushort4*>(hi)[i] = h4;
    reinterpret_cast<ushort4*>(lo)[i] = l4;
}

// ---------------- L6 combine: out = relu(sum_8 partial + bias) ---------------
__global__ __launch_bounds__(256) void combine_relu(
    const float* __restrict__ part, const float* __restrict__ bias,
    float* __restrict__ out)
{
    const int i = blockIdx.x * 256 + threadIdx.x;     // over 131072 float4
    const float4* p = (const float4*)part;
    float4 bb = ((const float4*)bias)[i & 127];
    float ox = bb.x, oy = bb.y, oz = bb.z, ow = bb.w;
    #pragma unroll
    for (int z = 0; z < 8; ++z) {
        float4 a = p[i + z * 131072];
        ox += a.x; oy += a.y; oz += a.z; ow += a.w;
    }
    float4 o;
    o.x = ox > 0.f ? ox : 0.f;
    o.y = oy > 0.f ? oy : 0.f;
    o.z = oz > 0.f ? oz : 0.f;
    o.w = ow > 0.f ? ow : 0.f;
    reinterpret_cast<float4*>(out)[i] = o;
}

// ---------------------------------------------------------------------------
extern "C" void kernel_launch(void* const* d_in, const int* in_sizes, int n_in,
                              void* d_out, int out_size, void* d_ws, size_t ws_size,
                              hipStream_t stream)
{
    const float* x     = (const float*)d_in[0];
    const float* emb_W = (const float*)d_in[1];
    const float* W_in  = (const float*)d_in[2];
    const float* b_in  = (const float*)d_in[3];
    const float* W_h   = (const float*)d_in[4];
    const float* b_h   = (const float*)d_in[5];
    const float* W_out = (const float*)d_in[6];
    const float* b_out = (const float*)d_in[7];
    float* out = (float*)d_out;

    char* w = (char*)d_ws;
    const size_t MB = 1 << 20;
    // phase-overlapped region [0..16MB)
    ushort* qhi    = (ushort*)(w);            // 1MB   (phase 1)
    ushort* wihi   = (ushort*)(w + 1*MB);     // 2MB   (phase 1)
    ushort* wilo   = (ushort*)(w + 3*MB);     // 2MB   (phase 1)
    float*  midpar = (float*)(w);             // 16MB  (phase 2: p0@0, p1@8MB)
    ushort* wohi   = (ushort*)(w);            // 2MB   (phase 3)
    ushort* wolo   = (ushort*)(w + 2*MB);     // 2MB   (phase 3)
    // persistent
    ushort* hhi    = (ushort*)(w + 16*MB);    // 4MB
    ushort* hlo    = (ushort*)(w + 20*MB);    // 4MB
    ushort* whhi   = (ushort*)(w + 24*MB);    // 8MB (dead after mids)
    ushort* whlo   = (ushort*)(w + 32*MB);    // 8MB (dead after mids)
    float*  l6par  = (float*)(w + 24*MB);     // 16MB (phase 3, reuses whh/whl)

    // 1) quantize (512 blocks) + wi/wh split (1280 blocks)
    fused_pre<<<1792, 256, 0, stream>>>(x, emb_W, W_in, W_h,
                                        qhi, wihi, wilo, whhi, whlo, out + NTOT);

    // 2) L1: h = relu(q @ W_in^T + b_in)  M=1024 N=2048 K=512 (A exact, 2-term)
    gemm_split<false, false><<<dim3(16, 16), 256, 0, stream>>>(
        qhi, nullptr, wihi, wilo, b_in, hhi, hlo, nullptr, HDIM, D_IN, D_IN);

    // 3) 4x mid: partial = h @ W_h^T (tile 128x256, splitK2, 128 blocks),
    //    combine -> h planes (in place)
    for (int l = 0; l < 4; ++l) {
        gemm_mid<<<dim3(8, 16), 256, 0, stream>>>(
            hhi, hlo, whhi, whlo, midpar, HDIM, HDIM, 1024);
        combine_mid<<<2048, 256, 0, stream>>>(midpar, b_h, hhi, hlo);
    }

    // 4) split W_out into freed phase-3 region
    wo_split<<<256, 256, 0, stream>>>(W_out, wohi, wolo);

    // 5) L6: partial = h @ W_out^T (tile 128x256, splitK8, 128 blocks)
    gemm_mid<<<dim3(2, 64), 256, 0, stream>>>(
        hhi, hlo, wohi, wolo, l6par, D_IN, HDIM, 256);

    // 6) combine 8 partials + bias + relu -> d_out
    combine_relu<<<512, 256, 0, stream>>>(l6par, b_out, out);
}

// Round 10
// 212.224 us; speedup vs baseline: 1.4381x; 1.4381x over previous
//
#include <hip/hip_runtime.h>
#include <hip/hip_bf16.h>
#include <math.h>

// ---------------------------------------------------------------------------
// VQ quantizer + 6-layer ReLU MLP via split-bf16 MFMA.
//   f32 GEMM ~= Ah*Bh + Ah*Bl + Al*Bh  (drop lo*lo ~2^-16 rel)
//   R10: R5 base (proven 217.7us) + L6 splitK8 (256 blocks; R5's 128-block
//        grid left half the CUs idle) + quantize k-loop unroll 4.
// Workspace map (40MB):
//   [0..16M)  phase1: qhi@0(1M), wihi@1M, wilo@3M   (dead after L1)
//             phase2: mid partial p0@0(8M), p1@8M
//             phase3: wohi@0(2M), wolo@2M
//   [16..24M) h planes: hhi@16M, hlo@20M
//   [24..40M) whhi@24M, whlo@32M (dead after mids) -> phase3: l6par@24M(16M)
// ---------------------------------------------------------------------------

#define B_ROWS 1024
#define D_IN   512
#define HDIM   2048
#define NTOT   (B_ROWS * D_IN)
#define NCODE  256
#define EDIM   8

typedef __attribute__((ext_vector_type(8))) short bf16x8;
typedef __attribute__((ext_vector_type(4))) float f32x4;

__device__ inline void gload_lds16(const void* g, void* l) {
    __builtin_amdgcn_global_load_lds(
        (const __attribute__((address_space(1))) void*)g,
        (__attribute__((address_space(3))) void*)l, 16, 0, 0);
}

__device__ inline ushort bf16_hi_bits(float v, float* hi_f) {
    __hip_bfloat16 h = __float2bfloat16(v);
    *hi_f = __bfloat162float(h);
    ushort u; __builtin_memcpy(&u, &h, 2); return u;
}
__device__ inline ushort bf16_bits(float v) {
    __hip_bfloat16 h = __float2bfloat16(v);
    ushort u; __builtin_memcpy(&u, &h, 2); return u;
}

// ---------------- fused: quantize (blocks 0..1023) + wi/wh split -------------
// R5-exact arithmetic. Per-k distance bits: d = RN(RN(sm+E[k]) - dot2),
// dot2 = sequential FMA of p2*w, p2 = 2*p (exact pow2 fold).
__global__ __launch_bounds__(256) void fused_pre(
    const float* __restrict__ x, const float* __restrict__ embW,
    const float* __restrict__ Wi, const float* __restrict__ Wh,
    ushort* __restrict__ qhi,
    ushort* __restrict__ wihi, ushort* __restrict__ wilo,
    ushort* __restrict__ whhi, ushort* __restrict__ whlo,
    float* __restrict__ loss_out)
{
    __shared__ float sWE[NCODE][12];   // w0..w7, E, pad -> 48B rows
    const int tid = threadIdx.x;

    if (blockIdx.x >= 1024) {
        // ---- weight split: 1280 blocks x 256 thr x 4 float4 ----
        const int sidx = blockIdx.x - 1024;
        #pragma unroll
        for (int s = 0; s < 4; ++s) {
            const int g = sidx * 1024 + s * 256 + tid;   // < 1310720
            const float* src; ushort* hi; ushort* lo; int j;
            if (g < 262144) { src = Wi; hi = wihi; lo = wilo; j = g; }
            else            { src = Wh; hi = whhi; lo = whlo; j = g - 262144; }
            float4 v = reinterpret_cast<const float4*>(src)[j];
            float f[4] = {v.x, v.y, v.z, v.w};
            ushort hh[4], ll[4];
            #pragma unroll
            for (int c = 0; c < 4; ++c) {
                float hf;
                hh[c] = bf16_hi_bits(f[c], &hf);
                ll[c] = bf16_bits(f[c] - hf);
            }
            ushort4 h4 = {hh[0], hh[1], hh[2], hh[3]};
            ushort4 l4 = {ll[0], ll[1], ll[2], ll[3]};
            reinterpret_cast<ushort4*>(hi)[j] = h4;
            reinterpret_cast<ushort4*>(lo)[j] = l4;
        }
        return;
    }

    // ---- quantize part ----
    {   // thread k: codebook row + E (numpy pairwise order)
        const float4 a4 = *reinterpret_cast<const float4*>(&embW[tid * EDIM]);
        const float4 b4 = *reinterpret_cast<const float4*>(&embW[tid * EDIM + 4]);
        float s0 = __fmul_rn(a4.x, a4.x), s1 = __fmul_rn(a4.y, a4.y);
        float s2 = __fmul_rn(a4.z, a4.z), s3 = __fmul_rn(a4.w, a4.w);
        float s4 = __fmul_rn(b4.x, b4.x), s5 = __fmul_rn(b4.y, b4.y);
        float s6 = __fmul_rn(b4.z, b4.z), s7 = __fmul_rn(b4.w, b4.w);
        float a = __fadd_rn(__fadd_rn(s0, s1), __fadd_rn(s2, s3));
        float b = __fadd_rn(__fadd_rn(s4, s5), __fadd_rn(s6, s7));
        sWE[tid][0] = a4.x; sWE[tid][1] = a4.y; sWE[tid][2] = a4.z; sWE[tid][3] = a4.w;
        sWE[tid][4] = b4.x; sWE[tid][5] = b4.y; sWE[tid][6] = b4.z; sWE[tid][7] = b4.w;
        sWE[tid][8] = __fadd_rn(a, b);
    }
    __syncthreads();

    const int nbase = blockIdx.x * 512 + tid;      // elems nbase, nbase+256

    float p2[2][EDIM], sm[2];
    #pragma unroll
    for (int j = 0; j < 2; ++j) {
        const float v = x[nbase + j * 256];
        float p[EDIM];
        #pragma unroll
        for (int e = 0; e < EDIM; ++e)
            p[e] = powf(v, (float)(e + 1));        // match np.power f32
        float a = __fadd_rn(__fadd_rn(p[0], p[1]), __fadd_rn(p[2], p[3]));
        float b = __fadd_rn(__fadd_rn(p[4], p[5]), __fadd_rn(p[6], p[7]));
        sm[j] = __fadd_rn(a, b);
        #pragma unroll
        for (int e = 0; e < EDIM; ++e)
            p2[j][e] = 2.0f * p[e];                // exact
    }

    float best[2] = {INFINITY, INFINITY};
    int   bi[2]   = {0, 0};
    #pragma unroll 4
    for (int k = 0; k < NCODE; ++k) {
        const float4 w0 = *reinterpret_cast<const float4*>(&sWE[k][0]);
        const float4 w1 = *reinterpret_cast<const float4*>(&sWE[k][4]);
        const float  Ek = sWE[k][8];
        #pragma unroll
        for (int j = 0; j < 2; ++j) {
            float dot = 0.f;
            dot = fmaf(p2[j][0], w0.x, dot); dot = fmaf(p2[j][1], w0.y, dot);
            dot = fmaf(p2[j][2], w0.z, dot); dot = fmaf(p2[j][3], w0.w, dot);
            dot = fmaf(p2[j][4], w1.x, dot); dot = fmaf(p2[j][5], w1.y, dot);
            dot = fmaf(p2[j][6], w1.z, dot); dot = fmaf(p2[j][7], w1.w, dot);
            float d = __fsub_rn(__fadd_rn(sm[j], Ek), dot);
            if (d < best[j]) { best[j] = d; bi[j] = k; }   // first-index-wins
        }
    }

    #pragma unroll
    for (int j = 0; j < 2; ++j) {
        const int n  = nbase + j * 256;
        const int bo = n & (B_ROWS - 1);
        const int dd = n >> 10;
        qhi[bo * D_IN + dd] = bf16_bits((float)bi[j]);     // 0..255 exact bf16
    }
    if (blockIdx.x == 0 && tid == 0) loss_out[0] = 0.0f;
}

// ---------------- wo split (after mids; writes into freed phase-3 region) ----
__global__ __launch_bounds__(256) void wo_split(
    const float* __restrict__ Wo, ushort* __restrict__ hi, ushort* __restrict__ lo)
{
    const int tid = threadIdx.x;
    #pragma unroll
    for (int s = 0; s < 4; ++s) {
        const int j = blockIdx.x * 1024 + s * 256 + tid;   // < 262144
        float4 v = reinterpret_cast<const float4*>(Wo)[j];
        float f[4] = {v.x, v.y, v.z, v.w};
        ushort hh[4], ll[4];
        #pragma unroll
        for (int c = 0; c < 4; ++c) {
            float hf;
            hh[c] = bf16_hi_bits(f[c], &hf);
            ll[c] = bf16_bits(f[c] - hf);
        }
        ushort4 h4 = {hh[0], hh[1], hh[2], hh[3]};
        ushort4 l4 = {ll[0], ll[1], ll[2], ll[3]};
        reinterpret_cast<ushort4*>(hi)[j] = h4;
        reinterpret_cast<ushort4*>(lo)[j] = l4;
    }
}

// ---------------- L1 GEMM (R3-proven): block 64x128, wave 32x64, BK=64 -------
template<bool ALO, bool PARTIAL>
__global__ __launch_bounds__(256) void gemm_split(
    const ushort* __restrict__ Ahi, const ushort* __restrict__ Alo,
    const ushort* __restrict__ Whi, const ushort* __restrict__ Wlo,
    const float* __restrict__ bias,
    ushort* __restrict__ Ohi, ushort* __restrict__ Olo,
    float* __restrict__ OF, int N, int K, int klen)
{
    constexpr int BUF = 49152;
    constexpr int OFF_AH = 0, OFF_AL = 8192, OFF_BH = 16384;
    __shared__ char lds[2 * BUF];

    const int tid = threadIdx.x, lane = tid & 63, wid = tid >> 6;

    const int gy = gridDim.y;
    const int nwg = gridDim.x * gy;
    int lin = blockIdx.x * gy + blockIdx.y;
    int q   = nwg >> 3;
    int sw  = (lin & 7) * q + (lin >> 3);
    int bx  = sw / gy, by2 = sw % gy;
    const int bm   = (by2 & 15) << 6;
    const int kz   = by2 >> 4;
    const int kbeg = kz * klen;
    const int bn   = bx << 7;

    const int wm = (wid >> 1) << 5;
    const int wn = (wid & 1) << 6;

    constexpr int NSEGW = ALO ? 12 : 10;
    const ushort* gp[NSEGW];
    uint ldsoff[NSEGW];
    #pragma unroll
    for (int i = 0; i < NSEGW; ++i) {
        int s = wid + i * 4;
        const ushort* pl; int row0, base, sip;
        if (ALO) {
            if (s < 8)       { pl = Ahi; row0 = bm; base = OFF_AH;         sip = s; }
            else if (s < 16) { pl = Alo; row0 = bm; base = OFF_AL;         sip = s - 8; }
            else if (s < 32) { pl = Whi; row0 = bn; base = OFF_BH;         sip = s - 16; }
            else             { pl = Wlo; row0 = bn; base = OFF_BH + 16384; sip = s - 32; }
        } else {
            if (s < 8)       { pl = Ahi; row0 = bm; base = OFF_AH;         sip = s; }
            else if (s < 24) { pl = Whi; row0 = bn; base = OFF_BH;         sip = s - 8; }
            else             { pl = Wlo; row0 = bn; base = OFF_BH + 16384; sip = s - 24; }
        }
        int r  = sip * 8 + (lane >> 3);
        int ch = (lane & 7) ^ (r & 7);
        gp[i]     = pl + (size_t)(row0 + r) * K + kbeg + ch * 8;
        ldsoff[i] = base + sip * 1024;
    }

    uint aoff[2][2], boff[4][2];
    #pragma unroll
    for (int f = 0; f < 2; ++f) {
        int ar = wm + f * 16 + (lane & 15);
        #pragma unroll
        for (int s = 0; s < 2; ++s) {
            int ch = (s * 4 + (lane >> 4)) ^ (ar & 7);
            aoff[f][s] = OFF_AH + ar * 128 + ch * 16;
        }
    }
    #pragma unroll
    for (int f = 0; f < 4; ++f) {
        int br = wn + f * 16 + (lane & 15);
        #pragma unroll
        for (int s = 0; s < 2; ++s) {
            int ch = (s * 4 + (lane >> 4)) ^ (br & 7);
            boff[f][s] = OFF_BH + br * 128 + ch * 16;
        }
    }

    auto stage = [&](int kt, int b) {
        #pragma unroll
        for (int i = 0; i < NSEGW; ++i)
            gload_lds16(gp[i] + kt * 64, lds + b * BUF + ldsoff[i]);
    };

    f32x4 acc[2][4] = {};
    const int NT = klen >> 6;

    stage(0, 0);
    __syncthreads();

    for (int t = 0; t < NT; ++t) {
        const int cur = t & 1;
        if (t + 1 < NT) stage(t + 1, cur ^ 1);

        const char* lb = lds + cur * BUF;
        bf16x8 aH[2][2], aL[2][2], bH[2][4], bL[2][4];
        #pragma unroll
        for (int s = 0; s < 2; ++s) {
            #pragma unroll
            for (int f = 0; f < 2; ++f) {
                aH[s][f] = *(const bf16x8*)(lb + aoff[f][s]);
                if constexpr (ALO) aL[s][f] = *(const bf16x8*)(lb + aoff[f][s] + 8192);
            }
            #pragma unroll
            for (int f = 0; f < 4; ++f) {
                bH[s][f] = *(const bf16x8*)(lb + boff[f][s]);
                bL[s][f] = *(const bf16x8*)(lb + boff[f][s] + 16384);
            }
        }
        #pragma unroll
        for (int s = 0; s < 2; ++s) {
            #pragma unroll
            for (int fm = 0; fm < 2; ++fm)
                #pragma unroll
                for (int fn = 0; fn < 4; ++fn)
                    acc[fm][fn] = __builtin_amdgcn_mfma_f32_16x16x32_bf16(
                        aH[s][fm], bH[s][fn], acc[fm][fn], 0, 0, 0);
            #pragma unroll
            for (int fm = 0; fm < 2; ++fm)
                #pragma unroll
                for (int fn = 0; fn < 4; ++fn)
                    acc[fm][fn] = __builtin_amdgcn_mfma_f32_16x16x32_bf16(
                        aH[s][fm], bL[s][fn], acc[fm][fn], 0, 0, 0);
            if constexpr (ALO) {
                #pragma unroll
                for (int fm = 0; fm < 2; ++fm)
                    #pragma unroll
                    for (int fn = 0; fn < 4; ++fn)
                        acc[fm][fn] = __builtin_amdgcn_mfma_f32_16x16x32_bf16(
                            aL[s][fm], bH[s][fn], acc[fm][fn], 0, 0, 0);
            }
        }
        __syncthreads();
    }

    #pragma unroll
    for (int fm = 0; fm < 2; ++fm) {
        #pragma unroll
        for (int fn = 0; fn < 4; ++fn) {
            const int col = bn + wn + fn * 16 + (lane & 15);
            const int rb  = bm + wm + fm * 16 + ((lane >> 4) << 2);
            if constexpr (PARTIAL) {
                #pragma unroll
                for (int r = 0; r < 4; ++r)
                    OF[(size_t)(kz * B_ROWS + rb + r) * N + col] = acc[fm][fn][r];
            } else {
                const float bc = bias[col];
                #pragma unroll
                for (int r = 0; r < 4; ++r) {
                    float v = acc[fm][fn][r] + bc;
                    v = v > 0.f ? v : 0.f;
                    float hf;
                    ushort hb = bf16_hi_bits(v, &hf);
                    Ohi[(size_t)(rb + r) * N + col] = hb;
                    Olo[(size_t)(rb + r) * N + col] = bf16_bits(v - hf);
                }
            }
        }
    }
}

// ---------------- mid/L6 GEMM (R5-proven): 128x128, wave 64x64, BK=64 --------
__global__ __launch_bounds__(256) void gemm_mid(
    const ushort* __restrict__ Ahi, const ushort* __restrict__ Alo,
    const ushort* __restrict__ Bhi, const ushort* __restrict__ Blo,
    float* __restrict__ OF, int N, int Kfull, int klen)
{
    constexpr int BUF = 65536;
    constexpr int OFF_A[2] = {0, 16384};
    constexpr int OFF_B[2] = {32768, 49152};
    __shared__ char lds[2 * BUF];

    const int tid = threadIdx.x, lane = tid & 63, wid = tid >> 6;

    const int gy = gridDim.y;
    const int nwg = gridDim.x * gy;
    int lin = blockIdx.x * gy + blockIdx.y;
    int q   = nwg >> 3;
    int sw  = (lin & 7) * q + (lin >> 3);
    int bx  = sw / gy, by2 = sw % gy;
    const int bm   = (by2 & 7) << 7;
    const int kz   = by2 >> 3;
    const int kbeg = kz * klen;
    const int bn   = bx << 7;

    const int wm = (wid >> 1) << 6;
    const int wn = (wid & 1) << 6;

    const int ch0 = (lane & 7) ^ (lane >> 3);
    const size_t kstep8 = (size_t)Kfull * 8;
    const ushort* gpb[4];
    uint lob[4];
    {
        const ushort* pls[4] = {Ahi, Alo, Bhi, Blo};
        const int row0s[4]   = {bm, bm, bn, bn};
        const uint bases[4]  = {OFF_A[0], OFF_A[1], OFF_B[0], OFF_B[1]};
        #pragma unroll
        for (int p = 0; p < 4; ++p) {
            gpb[p] = pls[p] + (size_t)(row0s[p] + wid * 32 + (lane >> 3)) * Kfull
                     + kbeg + ch0 * 8;
            lob[p] = bases[p] + wid * 4096;
        }
    }

    uint aoff[4][2], boff[4][2];
    #pragma unroll
    for (int f = 0; f < 4; ++f) {
        #pragma unroll
        for (int ks = 0; ks < 2; ++ks) {
            int ch = (ks * 4 + (lane >> 4)) ^ (lane & 7);
            aoff[f][ks] = OFF_A[0] + (wm + f * 16 + (lane & 15)) * 128 + ch * 16;
            boff[f][ks] = OFF_B[0] + (wn + f * 16 + (lane & 15)) * 128 + ch * 16;
        }
    }

    auto stage = [&](int kt, int b) {
        #pragma unroll
        for (int p = 0; p < 4; ++p)
            #pragma unroll
            for (int i = 0; i < 4; ++i)
                gload_lds16(gpb[p] + i * kstep8 + kt * 64,
                            lds + b * BUF + lob[p] + i * 1024);
    };

    f32x4 acc[4][4] = {};
    const int NT = klen >> 6;

    stage(0, 0);
    __syncthreads();

    for (int t = 0; t < NT; ++t) {
        const int cur = t & 1;
        if (t + 1 < NT) stage(t + 1, cur ^ 1);

        const char* lb = lds + cur * BUF;
        #pragma unroll
        for (int ks = 0; ks < 2; ++ks) {
            bf16x8 aH[4], aL[4], bH[4], bL[4];
            #pragma unroll
            for (int f = 0; f < 4; ++f) {
                aH[f] = *(const bf16x8*)(lb + aoff[f][ks]);
                aL[f] = *(const bf16x8*)(lb + aoff[f][ks] + 16384);
                bH[f] = *(const bf16x8*)(lb + boff[f][ks]);
                bL[f] = *(const bf16x8*)(lb + boff[f][ks] + 16384);
            }
            #pragma unroll
            for (int fm = 0; fm < 4; ++fm)
                #pragma unroll
                for (int fn = 0; fn < 4; ++fn)
                    acc[fm][fn] = __builtin_amdgcn_mfma_f32_16x16x32_bf16(
                        aH[fm], bH[fn], acc[fm][fn], 0, 0, 0);
            #pragma unroll
            for (int fm = 0; fm < 4; ++fm)
                #pragma unroll
                for (int fn = 0; fn < 4; ++fn)
                    acc[fm][fn] = __builtin_amdgcn_mfma_f32_16x16x32_bf16(
                        aH[fm], bL[fn], acc[fm][fn], 0, 0, 0);
            #pragma unroll
            for (int fm = 0; fm < 4; ++fm)
                #pragma unroll
                for (int fn = 0; fn < 4; ++fn)
                    acc[fm][fn] = __builtin_amdgcn_mfma_f32_16x16x32_bf16(
                        aL[fm], bH[fn], acc[fm][fn], 0, 0, 0);
        }
        __syncthreads();
    }

    #pragma unroll
    for (int fm = 0; fm < 4; ++fm) {
        #pragma unroll
        for (int fn = 0; fn < 4; ++fn) {
            const int col = bn + wn + fn * 16 + (lane & 15);
            const int rb  = bm + wm + fm * 16 + ((lane >> 4) << 2);
            #pragma unroll
            for (int r = 0; r < 4; ++r)
                OF[(size_t)(kz * B_ROWS + rb + r) * N + col] = acc[fm][fn][r];
        }
    }
}

// ---------------- mid combine: h = relu(p0+p1+bias) -> hi/lo planes ----------
__global__ __launch_bounds__(256) void combine_mid(
    const float* __restrict__ part, const float* __restrict__ bias,
    ushort* __restrict__ hi, ushort* __restrict__ lo)
{
    const int i = blockIdx.x * 256 + threadIdx.x;     // over 524288 float4
    const float4* p = (const float4*)part;
    float4 a = p[i], b = p[i + 524288];
    float4 bb = ((const float4*)bias)[i & 511];
    float f[4] = {a.x + b.x + bb.x, a.y + b.y + bb.y,
                  a.z + b.z + bb.z, a.w + b.w + bb.w};
    ushort hh[4], ll[4];
    #pragma unroll
    for (int c = 0; c < 4; ++c) {
        float v = f[c] > 0.f ? f[c] : 0.f;
        float hf;
        hh[c] = bf16_hi_bits(v, &hf);
        ll[c] = bf16_bits(v - hf);
    }
    ushort4 h4 = {hh[0], hh[1], hh[2], hh[3]};
    ushort4 l4 = {ll[0], ll[1], ll[2], ll[3]};
    reinterpret_cast<ushort4*>(hi)[i] = h4;
    reinterpret_cast<ushort4*>(lo)[i] = l4;
}

// ---------------- L6 combine: out = relu(sum_8 partial + bias) ---------------
__global__ __launch_bounds__(256) void combine_relu(
    const float* __restrict__ part, const float* __restrict__ bias,
    float* __restrict__ out)
{
    const int i = blockIdx.x * 256 + threadIdx.x;     // over 131072 float4
    const float4* p = (const float4*)part;
    float4 bb = ((const float4*)bias)[i & 127];
    float ox = bb.x, oy = bb.y, oz = bb.z, ow = bb.w;
    #pragma unroll
    for (int z = 0; z < 8; ++z) {
        float4 a = p[i + z * 131072];
        ox += a.x; oy += a.y; oz += a.z; ow += a.w;
    }
    float4 o;
    o.x = ox > 0.f ? ox : 0.f;
    o.y = oy > 0.f ? oy : 0.f;
    o.z = oz > 0.f ? oz : 0.f;
    o.w = ow > 0.f ? ow : 0.f;
    reinterpret_cast<float4*>(out)[i] = o;
}

// ---------------------------------------------------------------------------
extern "C" void kernel_launch(void* const* d_in, const int* in_sizes, int n_in,
                              void* d_out, int out_size, void* d_ws, size_t ws_size,
                              hipStream_t stream)
{
    const float* x     = (const float*)d_in[0];
    const float* emb_W = (const float*)d_in[1];
    const float* W_in  = (const float*)d_in[2];
    const float* b_in  = (const float*)d_in[3];
    const float* W_h   = (const float*)d_in[4];
    const float* b_h   = (const float*)d_in[5];
    const float* W_out = (const float*)d_in[6];
    const float* b_out = (const float*)d_in[7];
    float* out = (float*)d_out;

    char* w = (char*)d_ws;
    const size_t MB = 1 << 20;
    // phase-overlapped region [0..16MB)
    ushort* qhi    = (ushort*)(w);            // 1MB   (phase 1)
    ushort* wihi   = (ushort*)(w + 1*MB);     // 2MB   (phase 1)
    ushort* wilo   = (ushort*)(w + 3*MB);     // 2MB   (phase 1)
    float*  midpar = (float*)(w);             // 16MB  (phase 2: p0@0, p1@8MB)
    ushort* wohi   = (ushort*)(w);            // 2MB   (phase 3)
    ushort* wolo   = (ushort*)(w + 2*MB);     // 2MB   (phase 3)
    // persistent
    ushort* hhi    = (ushort*)(w + 16*MB);    // 4MB
    ushort* hlo    = (ushort*)(w + 20*MB);    // 4MB
    ushort* whhi   = (ushort*)(w + 24*MB);    // 8MB (dead after mids)
    ushort* whlo   = (ushort*)(w + 32*MB);    // 8MB (dead after mids)
    float*  l6par  = (float*)(w + 24*MB);     // 16MB (phase 3, reuses whh/whl)

    // 1) quantize + wi/wh split (fused); writes loss scalar at out[NTOT]
    fused_pre<<<2304, 256, 0, stream>>>(x, emb_W, W_in, W_h,
                                        qhi, wihi, wilo, whhi, whlo, out + NTOT);

    // 2) L1: h = relu(q @ W_in^T + b_in)  M=1024 N=2048 K=512 (A exact, 2-term)
    gemm_split<false, false><<<dim3(16, 16), 256, 0, stream>>>(
        qhi, nullptr, wihi, wilo, b_in, hhi, hlo, nullptr, HDIM, D_IN, D_IN);

    // 3) 4x mid: partial = h @ W_h^T (splitK2, 256 blocks), combine -> h planes
    for (int l = 0; l < 4; ++l) {
        gemm_mid<<<dim3(16, 16), 256, 0, stream>>>(
            hhi, hlo, whhi, whlo, midpar, HDIM, HDIM, 1024);
        combine_mid<<<2048, 256, 0, stream>>>(midpar, b_h, hhi, hlo);
    }

    // 4) split W_out into freed phase-3 region
    wo_split<<<256, 256, 0, stream>>>(W_out, wohi, wolo);

    // 5) L6: partial = h @ W_out^T (splitK8, 256 blocks)  M=1024 N=512 K=2048
    gemm_mid<<<dim3(4, 64), 256, 0, stream>>>(
        hhi, hlo, wohi, wolo, l6par, D_IN, HDIM, 256);

    // 6) combine 8 partials + bias + relu -> d_out
    combine_relu<<<512, 256, 0, stream>>>(l6par, b_out, out);
}